// Round 13
// baseline (147.373 us; speedup 1.0000x reference)
//
#include <hip/hip_runtime.h>

// Problem dims
#define Bb 8
#define Gg 512
#define Kk 64
#define Nn 1024
#define Mm 128
#define KM 8192           // Kk*Mm
#define GPB 16            // g per Pass-A block
#define NCH 32            // Gg/GPB partial chunks

struct K1Args {
  const float *z, *hs_grid, *hs_key, *z1w;
  const float *wra_w, *wrh_w, *wla_w, *wlh_w, *kR_w;
  const float *wla_b, *wlh_b, *kR_b, *wra_b, *wrh_b;
  const float *wcl_w, *wcl_b, *wcR_w;
  const float *mapL_w, *mapL_b, *fin_w, *fin_b;
  float *att, *laNum, *laDen, *ra, *Lk, *gbuf;
};

// ===========================================================================
// K1 (1024 threads):
//  [0,256)   Pass A: la partials + att   (thread = k-pair x m4, loops g)
//            -> ZERO barriers in main loop
//  [256,384) Pass B: ra[b,g,m]           (thread = g x m4, loops k)
//            -> ra reduction is intra-thread; 1 barrier total
//  [384,448) Lk chain
//  [448]     g-vector block
// gbuf: gv1[0:128) gv2[128:256) gu[256:384) gw1[384:512) gw2[512:640)
//       Cfull[640] fvecL[641:645)
// ===========================================================================
__global__ __launch_bounds__(1024) void K1(K1Args a) {
  __shared__ __align__(16) float smem[8192];   // 32 KB
  const int bid = blockIdx.x;
  const int t = threadIdx.x;

  if (bid < 256) {
    // ---------------- Pass A: la partials + att (barrier-free loop) -------
    float* s_hsgrid = smem;            // 2048
    const int b = bid >> 5;
    const int gblk = bid & 31;
    const int lane_m = t & 31;
    const int m4 = lane_m << 2;
    const int kgrp = t >> 5;           // 0..31

    const float* hgb = a.hs_grid + ((size_t)b * Gg + gblk * GPB) * Mm;
    for (int idx = t; idx < GPB * Mm; idx += 1024) s_hsgrid[idx] = hgb[idx];

    const int ofs0 = (kgrp * 2) * Mm + m4;
    const int ofs1 = ofs0 + Mm;
    const float zw0 = a.z1w[m4], zw1 = a.z1w[m4 + 1], zw2 = a.z1w[m4 + 2], zw3 = a.z1w[m4 + 3];

    float la_n[2][4], la_d[2][4];
#pragma unroll
    for (int i = 0; i < 2; ++i)
#pragma unroll
      for (int j = 0; j < 4; ++j) { la_n[i][j] = 0.f; la_d[i][j] = 0.f; }

    const float* zb = a.z + ((size_t)b * Gg + gblk * GPB) * (size_t)KM;
    float4 c0 = *reinterpret_cast<const float4*>(zb + ofs0);
    float4 c1 = *reinterpret_cast<const float4*>(zb + ofs1);

    __syncthreads();   // hsgrid staged; the ONLY barrier

    for (int gl = 0; gl < GPB; ++gl) {
      float4 n0 = c0, n1 = c1;
      if (gl < GPB - 1) {
        n0 = *reinterpret_cast<const float4*>(zb + (size_t)(gl + 1) * KM + ofs0);
        n1 = *reinterpret_cast<const float4*>(zb + (size_t)(gl + 1) * KM + ofs1);
      }
      const int g = gblk * GPB + gl;
      const float4 hg = *reinterpret_cast<const float4*>(s_hsgrid + gl * Mm + m4);
#pragma unroll
      for (int i = 0; i < 2; ++i) {
        const float4 v = (i == 0) ? c0 : c1;
        const int k = kgrp * 2 + i;
        const float e0 = __expf(v.x), e1 = __expf(v.y), e2 = __expf(v.z), e3 = __expf(v.w);
        la_n[i][0] += e0 * hg.x; la_n[i][1] += e1 * hg.y; la_n[i][2] += e2 * hg.z; la_n[i][3] += e3 * hg.w;
        la_d[i][0] += e0;        la_d[i][1] += e1;        la_d[i][2] += e2;        la_d[i][3] += e3;
        float ap = v.x * zw0 + v.y * zw1 + v.z * zw2 + v.w * zw3;
        ap += __shfl_xor(ap, 16); ap += __shfl_xor(ap, 8); ap += __shfl_xor(ap, 4);
        ap += __shfl_xor(ap, 2);  ap += __shfl_xor(ap, 1);
        if (lane_m == 0) a.att[((size_t)b * Gg + g) * Kk + k] = ap;
      }
      c0 = n0; c1 = n1;
    }

    const size_t base = ((size_t)(b * NCH + gblk)) * KM;
#pragma unroll
    for (int i = 0; i < 2; ++i) {
      const int k = kgrp * 2 + i;
      *reinterpret_cast<float4*>(a.laNum + base + k * Mm + m4) =
          make_float4(la_n[i][0], la_n[i][1], la_n[i][2], la_n[i][3]);
      *reinterpret_cast<float4*>(a.laDen + base + k * Mm + m4) =
          make_float4(la_d[i][0], la_d[i][1], la_d[i][2], la_d[i][3]);
    }
  } else if (bid < 384) {
    // ---------------- Pass B: ra[b,g,m] — intra-thread k-reduction --------
    float* s_hskey = smem;             // 8192 = 64 x 128 (32 KB)
    const int blk = bid - 256;         // 0..127
    const int b = blk >> 4;
    const int gch = blk & 15;          // 32 g each
    const int gslot = t >> 5;          // 0..31
    const int m4 = (t & 31) << 2;
    const int g = gch * 32 + gslot;

    const float* hkb = a.hs_key + (size_t)b * KM;
    for (int idx = t; idx < KM; idx += 1024) s_hskey[idx] = hkb[idx];
    __syncthreads();   // the ONLY barrier

    const float* zg = a.z + ((size_t)b * Gg + g) * (size_t)KM + m4;
    float n0 = 0.f, n1 = 0.f, n2 = 0.f, n3 = 0.f;
    float d0 = 0.f, d1 = 0.f, d2 = 0.f, d3 = 0.f;
#pragma unroll 4
    for (int k = 0; k < Kk; ++k) {
      const float4 v = *reinterpret_cast<const float4*>(zg + (size_t)k * Mm);
      const float4 hk = *reinterpret_cast<const float4*>(s_hskey + k * Mm + m4);
      const float e0 = __expf(v.x), e1 = __expf(v.y), e2 = __expf(v.z), e3 = __expf(v.w);
      n0 += e0 * hk.x; n1 += e1 * hk.y; n2 += e2 * hk.z; n3 += e3 * hk.w;
      d0 += e0; d1 += e1; d2 += e2; d3 += e3;
    }
    *reinterpret_cast<float4*>(a.ra + ((size_t)b * Gg + g) * Mm + m4) =
        make_float4(n0 / d0, n1 / d1, n2 / d2, n3 / d3);
  } else if (bid < 448) {
    // ---------------- Lk chain: lh = key@wcl.T + bl ; Lk = lh@wcR ----------
    float* s_w  = smem;          // 32 x 132 = 4224
    float* s_lh = smem + 4224;   // 8 x 132
    const int blk = bid - 384;
    const int b = blk >> 3, k8 = blk & 7;
    const int m = t & 127, kq = t >> 7;   // 0..7
    const int k = k8 * 8 + kq;
    float lh = 0.f;
    for (int hc = 0; hc < 4; ++hc) {
      for (int i = t; i < 4096; i += 1024) {
        const int mm = i >> 5, hh = i & 31;
        s_w[hh * 132 + mm] = a.wcl_w[(size_t)mm * Mm + hc * 32 + hh];
      }
      __syncthreads();
      const float* keyb = a.hs_key + ((size_t)b * Kk + k) * Mm + hc * 32;  // wave-uniform
      for (int hh = 0; hh < 32; ++hh) lh += keyb[hh] * s_w[hh * 132 + m];
      __syncthreads();
    }
    s_lh[kq * 132 + m] = lh + a.wcl_b[m];
    __syncthreads();
    float acc = 0.f;
    for (int mm = 0; mm < 128; ++mm)
      acc += s_lh[kq * 132 + mm] * a.wcR_w[(size_t)mm * Mm + m];
    a.Lk[((size_t)b * Kk + k) * Mm + m] = acc;
  } else {
    // ---------------- g-vector block ----------------
    float* s_fvec = smem;        // 260
    float* s_red  = smem + 260;  // 256
    if (t < 260) {
      float f = 0.f;
#pragma unroll
      for (int l = 0; l < 5; ++l) f += a.fin_w[l] * a.mapL_w[l * 260 + t];
      s_fvec[t] = f;
    }
    __syncthreads();
    const int h = t & 127, sel = t >> 7;   // 0..7
    if (sel < 5) {
      const float* W = (sel == 0) ? a.wla_w : (sel == 1) ? a.wlh_w :
                       (sel == 2) ? a.kR_w : (sel == 3) ? a.wra_w : a.wrh_w;
      const float* fv = (sel < 3) ? s_fvec : (s_fvec + 132);
      float g = 0.f;
      for (int mm = 0; mm < 128; ++mm) g += fv[mm] * W[(size_t)mm * Mm + h];
      a.gbuf[sel * 128 + h] = g;
    }
    if (t < 128) {
      s_red[t] = s_fvec[t] * (a.wla_b[t] + a.wlh_b[t] + a.kR_b[t]);
      s_red[128 + t] = s_fvec[132 + t] * (a.wra_b[t] + a.wrh_b[t]);
    }
    __syncthreads();
    if (t == 0) {
      float c1 = 0.f, c2 = 0.f;
      for (int i = 0; i < 128; ++i) { c1 += s_red[i]; c2 += s_red[128 + i]; }
      float C = a.fin_b[0];
#pragma unroll
      for (int l = 0; l < 5; ++l) C += a.fin_w[l] * a.mapL_b[l];
      // sum att_l = G = 512 exactly; sum att_r = K = 64 exactly
      a.gbuf[640] = C + 512.0f * c1 + 64.0f * c2;
#pragma unroll
      for (int e = 0; e < 4; ++e) a.gbuf[641 + e] = s_fvec[128 + e];
    }
  }
}

struct K2Args {
  const float *laNum, *laDen, *hs_key, *att, *ra, *hs_grid, *Lk, *hs_rec;
  const int *mask;
  const float *wRl, *gbuf;
  float *attlP, *attrPM, *attrPS, *attrPR, *pmT, *psT, *PSpT, *laDot, *keyDot;
};

// ===========================================================================
// K2: [0,64) laDot/keyDot | [64,128) att_l partials | [128,192) att_r with
//     inline rdot from divided ra | [192,704) scores tiles -> pm/ps/PSp
// ===========================================================================
__global__ __launch_bounds__(256) void K2(K2Args a) {
  __shared__ __align__(16) float smem[4944];
  const int bid = blockIdx.x;
  const int t = threadIdx.x;

  if (bid < 64) {
    // ---- laDot[b,k] = gv1 . (num/den), keyDot[b,k] = gv2 . key[b,k,:]
    const int b = bid >> 3, k8 = bid & 7;
    const int m = t & 127, kh = t >> 7;
    const float g1 = a.gbuf[m], g2 = a.gbuf[128 + m];
    float* sl = smem;            // 8*132
    float* sk = smem + 1056;     // 8*132
#pragma unroll
    for (int i = 0; i < 4; ++i) {
      const int k = k8 * 8 + kh * 4 + i;
      const float* np = a.laNum + (size_t)b * NCH * KM + (size_t)k * Mm + m;
      const float* dp = a.laDen + (size_t)b * NCH * KM + (size_t)k * Mm + m;
      float num = 0.f, den = 0.f;
#pragma unroll 8
      for (int p = 0; p < NCH; ++p) { num += np[(size_t)p * KM]; den += dp[(size_t)p * KM]; }
      sl[(kh * 4 + i) * 132 + m] = g1 * (num / den);
      sk[(kh * 4 + i) * 132 + m] = g2 * a.hs_key[((size_t)b * Kk + k) * Mm + m];
    }
    __syncthreads();
    const int rid = t >> 5, l32 = t & 31;
    float s1 = sl[rid * 132 + l32] + sl[rid * 132 + l32 + 32] +
               sl[rid * 132 + l32 + 64] + sl[rid * 132 + l32 + 96];
    float s2 = sk[rid * 132 + l32] + sk[rid * 132 + l32 + 32] +
               sk[rid * 132 + l32 + 64] + sk[rid * 132 + l32 + 96];
#pragma unroll
    for (int off = 16; off; off >>= 1) { s1 += __shfl_xor(s1, off); s2 += __shfl_xor(s2, off); }
    if (l32 == 0) {
      a.laDot[b * Kk + k8 * 8 + rid] = s1;
      a.keyDot[b * Kk + k8 * 8 + rid] = s2;
    }
  } else if (bid < 128) {
    // ---- att_l partials ----
    const int blk = bid - 64;
    const int b = blk >> 3, p = blk & 7;
    const int w = t >> 6, lane = t & 63;
    float acc = 0.f;
    for (int j = 0; j < 16; ++j) {
      const int g = p * 64 + w * 16 + j;
      const float av = a.att[((size_t)b * Gg + g) * Kk + lane];
      float mx = av;
      for (int off = 32; off; off >>= 1) mx = fmaxf(mx, __shfl_xor(mx, off));
      const float e = __expf(av - mx);
      float s = e;
      for (int off = 32; off; off >>= 1) s += __shfl_xor(s, off);
      acc += e / s;
    }
    float* sred = smem;
    sred[w * 64 + lane] = acc;
    __syncthreads();
    if (t < 64) a.attlP[(b * 8 + p) * 64 + t] = sred[t] + sred[64 + t] + sred[128 + t] + sred[192 + t];
  } else if (bid < 192) {
    // ---- att_r: inline rdot (from divided ra) + online partials per (b,gc) ----
    const int blk = bid - 128;
    const int b = blk >> 3, gc = blk & 7;
    float* s_gw   = smem;          // 256 (gw1, gw2)
    float* s_rdot = smem + 256;    // 64
    float* sm = smem + 320;        // 256
    float* ss = smem + 576;        // 256
    float* sr = smem + 832;        // 256
    s_gw[t] = a.gbuf[384 + t];
    __syncthreads();
    {
      const int gg = t >> 2, q = t & 3;
      const int g = gc * 64 + gg;
      const float* rp_ = a.ra + ((size_t)b * Gg + g) * Mm + q * 32;
      const float* hp = a.hs_grid + ((size_t)b * Gg + g) * Mm + q * 32;
      float acc = 0.f;
#pragma unroll
      for (int j4 = 0; j4 < 8; ++j4) {
        const float4 rv = *reinterpret_cast<const float4*>(rp_ + j4 * 4);
        const float4 hv = *reinterpret_cast<const float4*>(hp + j4 * 4);
        const int mb = q * 32 + j4 * 4;
        acc += s_gw[mb + 0] * rv.x + s_gw[128 + mb + 0] * hv.x;
        acc += s_gw[mb + 1] * rv.y + s_gw[128 + mb + 1] * hv.y;
        acc += s_gw[mb + 2] * rv.z + s_gw[128 + mb + 2] * hv.z;
        acc += s_gw[mb + 3] * rv.w + s_gw[128 + mb + 3] * hv.w;
      }
      acc += __shfl_xor(acc, 1);
      acc += __shfl_xor(acc, 2);
      if (q == 0) s_rdot[gg] = acc;
    }
    __syncthreads();
    const int k = t & 63, j4 = t >> 6;
    float m_ = -3.0e38f, s_ = 0.f, r_ = 0.f;
    for (int j = 0; j < 16; ++j) {
      const int gg = j4 * 16 + j;
      const float av = a.att[((size_t)b * Gg + gc * 64 + gg) * Kk + k];
      const float rv = s_rdot[gg];
      if (av > m_) {
        const float sc = __expf(m_ - av);
        s_ = s_ * sc + 1.0f; r_ = r_ * sc + rv; m_ = av;
      } else {
        const float e = __expf(av - m_);
        s_ += e; r_ += e * rv;
      }
    }
    sm[j4 * 64 + k] = m_; ss[j4 * 64 + k] = s_; sr[j4 * 64 + k] = r_;
    __syncthreads();
    if (t < 64) {
      float M = sm[t];
      for (int q = 1; q < 4; ++q) M = fmaxf(M, sm[q * 64 + t]);
      float S = 0.f, R = 0.f;
      for (int q = 0; q < 4; ++q) {
        const float e = __expf(sm[q * 64 + t] - M);
        S += ss[q * 64 + t] * e; R += sr[q * 64 + t] * e;
      }
      const int o = (b * 8 + gc) * 64 + t;
      a.attrPM[o] = M; a.attrPS[o] = S; a.attrPR[o] = R;
    }
  } else {
    // ---- scores tile: pm/ps/PSp partials (scores stay in registers) ----
    const int vb = bid - 192;
    const int b = vb >> 6, ntile = vb & 63;
    const int n0 = ntile * 16;
    const int k = t & 63;
    const int hq = __builtin_amdgcn_readfirstlane(t >> 6);
    float* s_acc = smem;          // 4096
    float* s_m   = smem + 4096;   // 256
    float* s_s   = smem + 4352;   // 256
    float* s_p   = smem + 4608;   // 256
    float* s_ru4 = smem + 4864;   // 64
    float* s_ru  = smem + 4928;   // 16
    float rLk[32];
    {
      const float* Lp = a.Lk + ((size_t)b * Kk + k) * Mm + hq * 32;
#pragma unroll
      for (int j = 0; j < 8; ++j) {
        const float4 v = *reinterpret_cast<const float4*>(Lp + j * 4);
        rLk[j * 4 + 0] = v.x; rLk[j * 4 + 1] = v.y;
        rLk[j * 4 + 2] = v.z; rLk[j * 4 + 3] = v.w;
      }
    }
    float acc[16];
    const float* rb = a.hs_rec + ((size_t)b * Nn + n0) * Mm + hq * 32;   // wave-uniform
#pragma unroll
    for (int r = 0; r < 16; ++r) {
      const float* rp = rb + r * Mm;
      float s = 0.f;
#pragma unroll
      for (int j4 = 0; j4 < 8; ++j4) {
        const float4 rv = *reinterpret_cast<const float4*>(rp + j4 * 4);
        s += rv.x * rLk[j4 * 4] + rv.y * rLk[j4 * 4 + 1] +
             rv.z * rLk[j4 * 4 + 2] + rv.w * rLk[j4 * 4 + 3];
      }
      acc[r] = s;
    }
#pragma unroll
    for (int r = 0; r < 16; ++r) s_acc[(hq * 16 + r) * 64 + k] = acc[r];
    if (t < 64) {   // ru[n] = gu . rec[n,:] partials
      const int rt = t >> 2, hc = t & 3;
      const float* rp = a.hs_rec + ((size_t)b * Nn + n0 + rt) * Mm + hc * 32;
      const float* gu = a.gbuf + 256 + hc * 32;
      float s = 0.f;
#pragma unroll
      for (int j = 0; j < 32; ++j) s += gu[j] * rp[j];
      s_ru4[rt * 4 + hc] = s;
    }
    __syncthreads();
    if (t < 16) s_ru[t] = s_ru4[t * 4] + s_ru4[t * 4 + 1] + s_ru4[t * 4 + 2] + s_ru4[t * 4 + 3];
    __syncthreads();
    const float wv = a.wRl[0];
    const bool msk = (a.mask[b * Kk + k] == 0);
    float m = -3.0e38f, ssum = 0.f, psum = 0.f;
    const int hq4 = (t >> 6) * 4;
#pragma unroll
    for (int q = 0; q < 4; ++q) {
      const int r = hq4 + q;
      float v = s_acc[r * 64 + k] + s_acc[(16 + r) * 64 + k] +
                s_acc[(32 + r) * 64 + k] + s_acc[(48 + r) * 64 + k];
      v = msk ? -1e10f : wv * v;
      const float runow = s_ru[r];
      if (v > m) {
        const float sc = __expf(m - v);
        ssum = ssum * sc + 1.0f; psum = psum * sc + runow; m = v;
      } else {
        const float e = __expf(v - m);
        ssum += e; psum += e * runow;
      }
    }
    s_m[(t >> 6) * 64 + k] = m; s_s[(t >> 6) * 64 + k] = ssum; s_p[(t >> 6) * 64 + k] = psum;
    __syncthreads();
    if (t < 64) {
      float M = fmaxf(fmaxf(s_m[t], s_m[64 + t]), fmaxf(s_m[128 + t], s_m[192 + t]));
      float S = 0.f, P = 0.f;
#pragma unroll
      for (int q = 0; q < 4; ++q) {
        const float e = __expf(s_m[q * 64 + t] - M);
        S += s_s[q * 64 + t] * e; P += s_p[q * 64 + t] * e;
      }
      const size_t o = ((size_t)b * 64 + ntile) * 64 + t;
      a.pmT[o] = M; a.psT[o] = S; a.PSpT[o] = P;
    }
  }
}

// ===========================================================================
// K3: per-b finale (8 blocks x 64 threads): scalar assembly
// ===========================================================================
__global__ __launch_bounds__(64) void K3(
    const float* __restrict__ attlP, const float* __restrict__ pmT,
    const float* __restrict__ psT, const float* __restrict__ PSpT,
    const float* __restrict__ attrPM, const float* __restrict__ attrPS,
    const float* __restrict__ attrPR,
    const float* __restrict__ laDot, const float* __restrict__ keyDot,
    const float* __restrict__ gbuf, const float* __restrict__ lig_rep,
    float* __restrict__ out)
{
  const int b = blockIdx.x, t = threadIdx.x;   // t = k
  float attl = 0.f;
#pragma unroll
  for (int p = 0; p < 8; ++p) attl += attlP[(b * 8 + p) * 64 + t];
  float M = -3.0e38f, S = 0.f, P = 0.f;
  for (int nt = 0; nt < 64; ++nt) {
    const size_t o = ((size_t)b * 64 + nt) * 64 + t;
    const float pm_ = pmT[o], ps_ = psT[o], pp = PSpT[o];
    if (pm_ > M) {
      const float sc = __expf(M - pm_);
      S = S * sc + ps_; P = P * sc + pp; M = pm_;
    } else {
      const float e = __expf(pm_ - M);
      S += ps_ * e; P += pp * e;
    }
  }
  float Mr = -3.0e38f, Sr = 0.f, Rr = 0.f;
  for (int p = 0; p < 8; ++p) {
    const int o = (b * 8 + p) * 64 + t;
    const float pm_ = attrPM[o], ps_ = attrPS[o], pr_ = attrPR[o];
    if (pm_ > Mr) {
      const float sc = __expf(Mr - pm_);
      Sr = Sr * sc + ps_; Rr = Rr * sc + pr_; Mr = pm_;
    } else {
      const float e = __expf(pm_ - Mr);
      Sr += ps_ * e; Rr += pr_ * e;
    }
  }
  float val = attl * (laDot[b * 64 + t] + keyDot[b * 64 + t] + P / S) + Rr / Sr;
#pragma unroll
  for (int off = 32; off; off >>= 1) val += __shfl_xor(val, off);
  if (t == 0) {
    float o = val + gbuf[640];
#pragma unroll
    for (int e = 0; e < 4; ++e) o += gbuf[641 + e] * lig_rep[b * 4 + e];
    out[b] = o;
  }
}

// ---------------------------------------------------------------------------
extern "C" void kernel_launch(void* const* d_in, const int* in_sizes, int n_in,
                              void* d_out, int out_size, void* d_ws, size_t ws_size,
                              hipStream_t stream) {
  float* w = (float*)d_ws;
  float* gbuf  = w;                       // 1024
  float* att   = gbuf + 1024;             // 262144
  float* laNum = att + Bb * Gg * Kk;      // 2097152
  float* laDen = laNum + Bb * NCH * KM;   // 2097152
  float* ra    = laDen + Bb * NCH * KM;   // 524288
  float* Lk    = ra + Bb * Gg * Mm;       // 65536
  float* attlP = Lk + Bb * Kk * Mm;       // 4096
  float* pmT   = attlP + Bb * 8 * 64;     // 32768
  float* psT   = pmT + Bb * 64 * 64;      // 32768
  float* PSpT  = psT + Bb * 64 * 64;      // 32768
  float* laDot = PSpT + Bb * 64 * 64;     // 512
  float* keyDot = laDot + Bb * Kk;        // 512
  float* attrPM = keyDot + Bb * Kk;       // 4096
  float* attrPS = attrPM + Bb * 8 * 64;   // 4096
  float* attrPR = attrPS + Bb * 8 * 64;   // 4096

  K1Args a1;
  a1.z = (const float*)d_in[0];
  a1.hs_grid = (const float*)d_in[1];
  a1.hs_key = (const float*)d_in[2];
  a1.z1w = (const float*)d_in[15];
  a1.wra_w = (const float*)d_in[7];  a1.wra_b = (const float*)d_in[8];
  a1.wrh_w = (const float*)d_in[9];  a1.wrh_b = (const float*)d_in[10];
  a1.wla_w = (const float*)d_in[11]; a1.wla_b = (const float*)d_in[12];
  a1.wlh_w = (const float*)d_in[13]; a1.wlh_b = (const float*)d_in[14];
  a1.wcl_w = (const float*)d_in[19]; a1.wcl_b = (const float*)d_in[20];
  a1.wcR_w = (const float*)d_in[17];
  a1.kR_w  = (const float*)d_in[21]; a1.kR_b = (const float*)d_in[22];
  a1.mapL_w = (const float*)d_in[23]; a1.mapL_b = (const float*)d_in[24];
  a1.fin_w = (const float*)d_in[25]; a1.fin_b = (const float*)d_in[26];
  a1.att = att; a1.laNum = laNum; a1.laDen = laDen;
  a1.ra = ra; a1.Lk = Lk; a1.gbuf = gbuf;

  K2Args a2;
  a2.laNum = laNum; a2.laDen = laDen;
  a2.hs_key = (const float*)d_in[2];
  a2.att = att; a2.ra = ra;
  a2.hs_grid = (const float*)d_in[1];
  a2.Lk = Lk;
  a2.hs_rec = (const float*)d_in[4];
  a2.mask = (const int*)d_in[6];
  a2.wRl = (const float*)d_in[5];
  a2.gbuf = gbuf;
  a2.attlP = attlP;
  a2.attrPM = attrPM; a2.attrPS = attrPS; a2.attrPR = attrPR;
  a2.pmT = pmT; a2.psT = psT; a2.PSpT = PSpT;
  a2.laDot = laDot; a2.keyDot = keyDot;

  K1<<<449, 1024, 0, stream>>>(a1);
  K2<<<704, 256, 0, stream>>>(a2);
  K3<<<Bb, 64, 0, stream>>>(attlP, pmT, psT, PSpT, attrPM, attrPS, attrPR,
                            laDot, keyDot, gbuf, (const float*)d_in[3],
                            (float*)d_out);
}

// Round 14
// 89.402 us; speedup vs baseline: 1.6484x; 1.6484x over previous
//
#include <hip/hip_runtime.h>

// Problem dims
#define Bb 8
#define Gg 512
#define Kk 64
#define Nn 1024
#define Mm 128
#define KM (Kk * Mm)      // 8192
#define GPB 16            // g per block in kA z-pass
#define NCH 32            // Gg/GPB partial chunks

struct P7 { const float* p[7]; };

// ===========================================================================
// KA: z-pass (blocks 0..255) + 7x weight transpose (blocks 256..367)
//   ra[b,g,m], att[b,g,k], laNum/laDen partials per 16-g chunk
//   hs_key fragment lives in registers (constant per thread across g-loop).
// ===========================================================================
__global__ __launch_bounds__(1024) void kA(
    const float* __restrict__ z, const float* __restrict__ hs_grid,
    const float* __restrict__ hs_key, const float* __restrict__ z1w,
    P7 ptrs, float* __restrict__ wT,
    float* __restrict__ raOut, float* __restrict__ attOut,
    float* __restrict__ laNum, float* __restrict__ laDen)
{
  __shared__ __align__(16) float smem[10240];   // 41 KB
  const int bid = blockIdx.x;
  const int t = threadIdx.x;

  if (bid >= Bb * NCH) {
    // ---- weight transpose: 112 blocks, 32x32 tiles ----
    float* tile = smem;                          // 32*33
    const int r = bid - Bb * NCH;
    const int mat = r >> 4, tl = r & 15;
    const int xo = (tl & 3) * 32, y0 = (tl >> 2) * 32;
    const int tx = t & 31, ty = t >> 5;
    const float* src = ptrs.p[mat];
    float* dst = wT + (size_t)mat * Mm * Mm;
    tile[ty * 33 + tx] = src[(size_t)(y0 + ty) * Mm + xo + tx];
    __syncthreads();
    dst[(size_t)(xo + ty) * Mm + y0 + tx] = tile[tx * 33 + ty];
    return;
  }

  float* s_hsgrid = smem;            // 2048
  float* s_rn     = smem + 2048;     // 2 x 2048 (double buffered)
  float* s_rd     = smem + 6144;     // 2 x 2048

  const int b = bid >> 5;
  const int gblk = bid & 31;
  const int lane_m = t & 31;
  const int m4 = lane_m << 2;
  const int kgrp = t >> 5;           // 0..31
  const int wv = t >> 6;             // 0..15

  const float* hgb = hs_grid + ((size_t)b * Gg + gblk * GPB) * Mm;
  for (int idx = t; idx < GPB * Mm; idx += 1024) s_hsgrid[idx] = hgb[idx];

  const int ofs0 = (kgrp * 2) * Mm + m4;
  const int ofs1 = ofs0 + Mm;
  // hs_key fragment in registers — constant across the g loop
  const float4 hk0 = *reinterpret_cast<const float4*>(hs_key + (size_t)b * KM + ofs0);
  const float4 hk1 = *reinterpret_cast<const float4*>(hs_key + (size_t)b * KM + ofs1);

  const float zw0 = z1w[m4], zw1 = z1w[m4 + 1], zw2 = z1w[m4 + 2], zw3 = z1w[m4 + 3];

  float la_n[2][4], la_d[2][4];
#pragma unroll
  for (int i = 0; i < 2; ++i)
#pragma unroll
    for (int j = 0; j < 4; ++j) { la_n[i][j] = 0.f; la_d[i][j] = 0.f; }

  const float* zb = z + ((size_t)b * Gg + gblk * GPB) * (size_t)KM;
  float4 c0 = *reinterpret_cast<const float4*>(zb + ofs0);
  float4 c1 = *reinterpret_cast<const float4*>(zb + ofs1);

  __syncthreads();   // staging ready

  for (int gl = 0; gl < GPB; ++gl) {
    float4 n0 = c0, n1 = c1;
    if (gl < GPB - 1) {
      n0 = *reinterpret_cast<const float4*>(zb + (size_t)(gl + 1) * KM + ofs0);
      n1 = *reinterpret_cast<const float4*>(zb + (size_t)(gl + 1) * KM + ofs1);
    }
    const int g = gblk * GPB + gl;
    const float4 hg = *reinterpret_cast<const float4*>(s_hsgrid + gl * Mm + m4);
    float rn0 = 0, rn1 = 0, rn2 = 0, rn3 = 0, rd0 = 0, rd1 = 0, rd2 = 0, rd3 = 0;
#pragma unroll
    for (int i = 0; i < 2; ++i) {
      const float4 v = (i == 0) ? c0 : c1;
      const float4 hk = (i == 0) ? hk0 : hk1;
      const int k = kgrp * 2 + i;
      const float e0 = __expf(v.x), e1 = __expf(v.y), e2 = __expf(v.z), e3 = __expf(v.w);
      la_n[i][0] += e0 * hg.x; la_n[i][1] += e1 * hg.y; la_n[i][2] += e2 * hg.z; la_n[i][3] += e3 * hg.w;
      la_d[i][0] += e0;        la_d[i][1] += e1;        la_d[i][2] += e2;        la_d[i][3] += e3;
      rn0 += e0 * hk.x; rn1 += e1 * hk.y; rn2 += e2 * hk.z; rn3 += e3 * hk.w;
      rd0 += e0; rd1 += e1; rd2 += e2; rd3 += e3;
      float ap = v.x * zw0 + v.y * zw1 + v.z * zw2 + v.w * zw3;
      ap += __shfl_xor(ap, 16); ap += __shfl_xor(ap, 8); ap += __shfl_xor(ap, 4);
      ap += __shfl_xor(ap, 2);  ap += __shfl_xor(ap, 1);
      if (lane_m == 0) attOut[((size_t)b * Gg + g) * Kk + k] = ap;
    }
    rn0 += __shfl_xor(rn0, 32); rn1 += __shfl_xor(rn1, 32); rn2 += __shfl_xor(rn2, 32); rn3 += __shfl_xor(rn3, 32);
    rd0 += __shfl_xor(rd0, 32); rd1 += __shfl_xor(rd1, 32); rd2 += __shfl_xor(rd2, 32); rd3 += __shfl_xor(rd3, 32);
    float* rnB = s_rn + (gl & 1) * 2048;
    float* rdB = s_rd + (gl & 1) * 2048;
    if ((t & 63) < 32) {
      *reinterpret_cast<float4*>(rnB + wv * Mm + m4) = make_float4(rn0, rn1, rn2, rn3);
      *reinterpret_cast<float4*>(rdB + wv * Mm + m4) = make_float4(rd0, rd1, rd2, rd3);
    }
    __syncthreads();
    if (t < Mm) {
      float num = 0.f, den = 0.f;
#pragma unroll
      for (int ww = 0; ww < 16; ++ww) { num += rnB[ww * Mm + t]; den += rdB[ww * Mm + t]; }
      raOut[((size_t)b * Gg + g) * Mm + t] = num / den;
    }
    c0 = n0; c1 = n1;
  }

  const size_t base = ((size_t)(b * NCH + gblk)) * KM;
#pragma unroll
  for (int i = 0; i < 2; ++i) {
    const int k = kgrp * 2 + i;
    *reinterpret_cast<float4*>(laNum + base + k * Mm + m4) =
        make_float4(la_n[i][0], la_n[i][1], la_n[i][2], la_n[i][3]);
    *reinterpret_cast<float4*>(laDen + base + k * Mm + m4) =
        make_float4(la_d[i][0], la_d[i][1], la_d[i][2], la_d[i][3]);
  }
}

// ===========================================================================
// KB: [0,256) la-reduce | [256,320) att_l partials | [320,384) att_r partials
//     | [384,448) Lk chain: lh = key@wclT + bl ; Lk[k,h] = sum_m lh[k,m]*wcR[m,h]
// ===========================================================================
__global__ __launch_bounds__(256) void kB(
    const float* __restrict__ laNum, const float* __restrict__ laDen, float* __restrict__ la,
    const float* __restrict__ att, float* __restrict__ attlP,
    float* __restrict__ attrPM, float* __restrict__ attrPS,
    const float* __restrict__ hs_key, const float* __restrict__ wT,
    const float* __restrict__ wcR_w, const float* __restrict__ wcl_b,
    float* __restrict__ Lk)
{
  __shared__ __align__(16) float smem[1088];
  const int bid = blockIdx.x;
  const int t = threadIdx.x;

  if (bid < 256) {
    const int idx = bid * 256 + t;
    const int b = idx >> 13, r = idx & 8191;
    const float* np = laNum + (size_t)b * NCH * KM + r;
    const float* dp = laDen + (size_t)b * NCH * KM + r;
    float num = 0.f, den = 0.f;
#pragma unroll 8
    for (int p = 0; p < NCH; ++p) { num += np[(size_t)p * KM]; den += dp[(size_t)p * KM]; }
    la[idx] = num / den;
  } else if (bid < 320) {
    const int blk = bid - 256;
    const int b = blk >> 3, p = blk & 7;
    const int w = t >> 6, lane = t & 63;
    float acc = 0.f;
    for (int j = 0; j < 16; ++j) {
      const int g = p * 64 + w * 16 + j;
      const float a = att[((size_t)b * Gg + g) * Kk + lane];
      float mx = a;
      for (int off = 32; off; off >>= 1) mx = fmaxf(mx, __shfl_xor(mx, off));
      const float e = __expf(a - mx);
      float s = e;
      for (int off = 32; off; off >>= 1) s += __shfl_xor(s, off);
      acc += e / s;
    }
    float* sred = smem;
    sred[w * 64 + lane] = acc;
    __syncthreads();
    if (t < 64) attlP[(b * 8 + p) * 64 + t] = sred[t] + sred[64 + t] + sred[128 + t] + sred[192 + t];
  } else if (bid < 384) {
    const int blk = bid - 320;
    const int b = blk >> 3, gc = blk & 7;
    const int k = t & 63, j4 = t >> 6;
    float m = -1e30f, s = 0.f;
    for (int j = 0; j < 16; ++j) {
      const int g = gc * 64 + j4 * 16 + j;
      const float a = att[((size_t)b * Gg + g) * Kk + k];
      if (a > m) { s = s * __expf(m - a) + 1.0f; m = a; }
      else s += __expf(a - m);
    }
    float* sm = smem;          // 256
    float* ss = smem + 256;    // 256
    sm[j4 * 64 + k] = m; ss[j4 * 64 + k] = s;
    __syncthreads();
    if (t < 64) {
      float M = sm[t];
      for (int q = 1; q < 4; ++q) M = fmaxf(M, sm[q * 64 + t]);
      float S = 0.f;
      for (int q = 0; q < 4; ++q) S += ss[q * 64 + t] * __expf(sm[q * 64 + t] - M);
      attrPM[(b * 8 + gc) * 64 + t] = M;
      attrPS[(b * 8 + gc) * 64 + t] = S;
    }
  } else {
    // ---- Lk chain: 64 blocks, one per (b, 8-k tile) ----
    const int blk = bid - 384;
    const int b = blk >> 3, k8 = blk & 7;
    float* s_lh = smem;                   // 8 x 132
    const int m = t & 127;
    const int half = __builtin_amdgcn_readfirstlane(t >> 7);
    const float* wclT = wT + 5 * 16384;
    {
      const float* keyb = hs_key + ((size_t)b * Kk + k8 * 8 + half * 4) * Mm;  // wave-uniform
      float a0 = 0.f, a1 = 0.f, a2 = 0.f, a3 = 0.f;
      for (int h4 = 0; h4 < 32; ++h4) {
        const float4 r0v = *reinterpret_cast<const float4*>(keyb + h4 * 4);
        const float4 r1v = *reinterpret_cast<const float4*>(keyb + 128 + h4 * 4);
        const float4 r2v = *reinterpret_cast<const float4*>(keyb + 256 + h4 * 4);
        const float4 r3v = *reinterpret_cast<const float4*>(keyb + 384 + h4 * 4);
        const float w0 = wclT[(size_t)(h4 * 4 + 0) * Mm + m];
        const float w1 = wclT[(size_t)(h4 * 4 + 1) * Mm + m];
        const float w2 = wclT[(size_t)(h4 * 4 + 2) * Mm + m];
        const float w3 = wclT[(size_t)(h4 * 4 + 3) * Mm + m];
        a0 += r0v.x * w0 + r0v.y * w1 + r0v.z * w2 + r0v.w * w3;
        a1 += r1v.x * w0 + r1v.y * w1 + r1v.z * w2 + r1v.w * w3;
        a2 += r2v.x * w0 + r2v.y * w1 + r2v.z * w2 + r2v.w * w3;
        a3 += r3v.x * w0 + r3v.y * w1 + r3v.z * w2 + r3v.w * w3;
      }
      const float bm = wcl_b[m];
      s_lh[(half * 4 + 0) * 132 + m] = a0 + bm;
      s_lh[(half * 4 + 1) * 132 + m] = a1 + bm;
      s_lh[(half * 4 + 2) * 132 + m] = a2 + bm;
      s_lh[(half * 4 + 3) * 132 + m] = a3 + bm;
    }
    __syncthreads();
    {
      const int h = m;
      const int r0 = half * 4;
      float b0 = 0.f, b1 = 0.f, b2 = 0.f, b3 = 0.f;
      for (int mq = 0; mq < 32; ++mq) {
        const float4 L0 = *reinterpret_cast<const float4*>(&s_lh[(r0 + 0) * 132 + mq * 4]);
        const float4 L1 = *reinterpret_cast<const float4*>(&s_lh[(r0 + 1) * 132 + mq * 4]);
        const float4 L2 = *reinterpret_cast<const float4*>(&s_lh[(r0 + 2) * 132 + mq * 4]);
        const float4 L3 = *reinterpret_cast<const float4*>(&s_lh[(r0 + 3) * 132 + mq * 4]);
        const float w0 = wcR_w[(size_t)(mq * 4 + 0) * Mm + h];
        const float w1 = wcR_w[(size_t)(mq * 4 + 1) * Mm + h];
        const float w2 = wcR_w[(size_t)(mq * 4 + 2) * Mm + h];
        const float w3 = wcR_w[(size_t)(mq * 4 + 3) * Mm + h];
        b0 += L0.x * w0 + L0.y * w1 + L0.z * w2 + L0.w * w3;
        b1 += L1.x * w0 + L1.y * w1 + L1.z * w2 + L1.w * w3;
        b2 += L2.x * w0 + L2.y * w1 + L2.z * w2 + L2.w * w3;
        b3 += L3.x * w0 + L3.y * w1 + L3.z * w2 + L3.w * w3;
      }
      const size_t ob = ((size_t)b * Kk + k8 * 8 + r0) * Mm + h;
      Lk[ob] = b0; Lk[ob + Mm] = b1; Lk[ob + 2 * Mm] = b2; Lk[ob + 3 * Mm] = b3;
    }
  }
}

// ===========================================================================
// KC: [0,64) att_r final | [64,576) scores = rec @ Lk^T + softmax partials
// ===========================================================================
__global__ __launch_bounds__(256) void kC(
    const float* __restrict__ att, const float* __restrict__ attrPM, const float* __restrict__ attrPS,
    float* __restrict__ att_r,
    const float* __restrict__ hs_rec, const float* __restrict__ Lk,
    const int* __restrict__ mask, const float* __restrict__ wRl,
    float* __restrict__ scores, float* __restrict__ pmT, float* __restrict__ psT)
{
  __shared__ __align__(16) float smem[4608];
  const int bid = blockIdx.x;
  const int t = threadIdx.x;

  if (bid < 64) {
    const int b = bid >> 3, gc = bid & 7;
    const int k = t & 63, grp = t >> 6;
    float* Mx = smem;
    float* S = smem + 64;
    if (t < 64) {
      float M = -1e30f;
      for (int p = 0; p < 8; ++p) M = fmaxf(M, attrPM[(b * 8 + p) * 64 + t]);
      float s = 0.f;
      for (int p = 0; p < 8; ++p) s += attrPS[(b * 8 + p) * 64 + t] * __expf(attrPM[(b * 8 + p) * 64 + t] - M);
      Mx[t] = M; S[t] = s;
    }
    __syncthreads();
    const float Mk = Mx[k], Sk = S[k];
    for (int j = 0; j < 16; ++j) {
      const int g = gc * 64 + grp * 16 + j;
      float p = __expf(att[((size_t)b * Gg + g) * Kk + k] - Mk) / Sk;
      for (int off = 32; off; off >>= 1) p += __shfl_xor(p, off);
      if (k == 0) att_r[b * Gg + g] = p;
    }
  } else {
    const int vb = bid - 64;
    const int b = vb >> 6, ntile = vb & 63;
    const int n0 = ntile * 16;
    const int k = t & 63;
    const int hq = __builtin_amdgcn_readfirstlane(t >> 6);
    // preload this (k, hq) fragment of Lk into registers
    float rLk[32];
    {
      const float* Lp = Lk + ((size_t)b * Kk + k) * Mm + hq * 32;
#pragma unroll
      for (int j = 0; j < 8; ++j) {
        const float4 v = *reinterpret_cast<const float4*>(Lp + j * 4);
        rLk[j * 4 + 0] = v.x; rLk[j * 4 + 1] = v.y;
        rLk[j * 4 + 2] = v.z; rLk[j * 4 + 3] = v.w;
      }
    }
    float acc[16];
    const float* rb = hs_rec + ((size_t)b * Nn + n0) * Mm + hq * 32;   // wave-uniform
#pragma unroll
    for (int r = 0; r < 16; ++r) {
      const float* rp = rb + r * Mm;
      float s = 0.f;
#pragma unroll
      for (int j4 = 0; j4 < 8; ++j4) {
        const float4 rv = *reinterpret_cast<const float4*>(rp + j4 * 4);  // s_load_dwordx4
        s += rv.x * rLk[j4 * 4] + rv.y * rLk[j4 * 4 + 1] +
             rv.z * rLk[j4 * 4 + 2] + rv.w * rLk[j4 * 4 + 3];
      }
      acc[r] = s;
    }
    float* s_acc = smem;          // 4096
    float* s_m   = smem + 4096;   // 256
    float* s_s   = smem + 4352;   // 256
#pragma unroll
    for (int r = 0; r < 16; ++r) s_acc[(hq * 16 + r) * 64 + k] = acc[r];
    __syncthreads();
    const float wv = wRl[0];
    const bool msk = (mask[b * Kk + k] == 0);
    float m = -3.0e38f, ssum = 0.f;
    for (int q = 0; q < 4; ++q) {
      const int idx = q * 256 + t;
      const int r = idx >> 6, kk = idx & 63;
      float v = s_acc[r * 64 + kk] + s_acc[(16 + r) * 64 + kk] +
                s_acc[(32 + r) * 64 + kk] + s_acc[(48 + r) * 64 + kk];
      v = msk ? -1e10f : wv * v;
      scores[((size_t)b * Nn + n0 + r) * Kk + kk] = v;
      if (v > m) { ssum = ssum * __expf(m - v) + 1.0f; m = v; }
      else ssum += __expf(v - m);
    }
    s_m[hq * 64 + k] = m; s_s[hq * 64 + k] = ssum;
    __syncthreads();
    if (t < 64) {
      float M = fmaxf(fmaxf(s_m[t], s_m[64 + t]), fmaxf(s_m[128 + t], s_m[192 + t]));
      float S = 0.f;
#pragma unroll
      for (int q = 0; q < 4; ++q) S += s_s[q * 64 + t] * __expf(s_m[q * 64 + t] - M);
      pmT[((size_t)b * 64 + ntile) * 64 + t] = M;
      psT[((size_t)b * 64 + ntile) * 64 + t] = S;
    }
  }
}

// ===========================================================================
// KD: weighted-sum partial reductions (512 threads)
// ===========================================================================
__global__ __launch_bounds__(512) void kD(
    const float* __restrict__ scores, const float* __restrict__ hs_rec,
    const float* __restrict__ pmT, const float* __restrict__ psT,
    const float* __restrict__ attlP, const float* __restrict__ att_r,
    const float* __restrict__ ra, const float* __restrict__ hs_grid,
    const float* __restrict__ la, const float* __restrict__ hs_key,
    float* __restrict__ uP, float* __restrict__ w1P, float* __restrict__ w2P,
    float* __restrict__ w0P, float* __restrict__ v1, float* __restrict__ v2,
    float* __restrict__ sAv)
{
  __shared__ float sm[1280];
  __shared__ float s_attl[64];
  __shared__ float sM[64], sSi[64];
  const int bid = blockIdx.x;
  const int t = threadIdx.x;

  if (bid < 64) {
    const int b = bid >> 3, nc = bid & 7;
    if (t < 64) {
      float a = 0.f;
      for (int p = 0; p < 8; ++p) a += attlP[(b * 8 + p) * 64 + t];
      s_attl[t] = a;
      float M = -3.0e38f;
      for (int nt = 0; nt < 64; ++nt) M = fmaxf(M, pmT[((size_t)b * 64 + nt) * 64 + t]);
      float S = 0.f;
      for (int nt = 0; nt < 64; ++nt)
        S += psT[((size_t)b * 64 + nt) * 64 + t] * __expf(pmT[((size_t)b * 64 + nt) * 64 + t] - M);
      sM[t] = M; sSi[t] = 1.0f / S;
    }
    __syncthreads();
    const int n = t >> 2, ks = t & 3;
    const float* sc = scores + ((size_t)b * Nn + nc * 128 + n) * Kk + ks * 16;
    float qp = 0.f;
#pragma unroll
    for (int j = 0; j < 16; ++j) {
      const int k = ks * 16 + j;
      qp += s_attl[k] * __expf(sc[j] - sM[k]) * sSi[k];
    }
    sm[n * 4 + ks] = qp;
    __syncthreads();
    float* q = sm + 512;
    if (t < 128) q[t] = sm[t * 4] + sm[t * 4 + 1] + sm[t * 4 + 2] + sm[t * 4 + 3];
    __syncthreads();
    const int h = t & 127, nq = t >> 7;
    float acc = 0.f;
    const float* hr = hs_rec + ((size_t)b * Nn + nc * 128 + nq * 32) * Mm + h;
    for (int j = 0; j < 32; ++j) acc += q[nq * 32 + j] * hr[(size_t)j * Mm];
    float* red = sm + 640;
    red[nq * 128 + h] = acc;
    __syncthreads();
    if (t < 128) uP[((size_t)b * 8 + nc) * 128 + t] = red[t] + red[128 + t] + red[256 + t] + red[384 + t];
  } else if (bid < 128) {
    const int blk = bid - 64;
    const int b = blk >> 3, gc = blk & 7;
    float* s_ar = sm + 1152;   // 64
    if (t < 64) s_ar[t] = att_r[b * Gg + gc * 64 + t];
    __syncthreads();
    const int h = t & 127, gq = t >> 7;
    float a1 = 0.f, a2 = 0.f;
    const float* rp = ra + ((size_t)b * Gg + gc * 64 + gq * 16) * Mm + h;
    const float* gp = hs_grid + ((size_t)b * Gg + gc * 64 + gq * 16) * Mm + h;
    for (int j = 0; j < 16; ++j) {
      const float w = s_ar[gq * 16 + j];
      a1 += w * rp[(size_t)j * Mm];
      a2 += w * gp[(size_t)j * Mm];
    }
    float* r1 = sm;
    float* r2 = sm + 512;
    r1[gq * 128 + h] = a1; r2[gq * 128 + h] = a2;
    __syncthreads();
    if (t < 128) {
      w1P[((size_t)b * 8 + gc) * 128 + t] = r1[t] + r1[128 + t] + r1[256 + t] + r1[384 + t];
      w2P[((size_t)b * 8 + gc) * 128 + t] = r2[t] + r2[128 + t] + r2[256 + t] + r2[384 + t];
    }
    if (t == 0) {
      float s = 0.f;
      for (int j = 0; j < 64; ++j) s += s_ar[j];
      w0P[b * 8 + gc] = s;
    }
  } else {
    const int b = bid - 128;
    if (t < 64) {
      float a = 0.f;
      for (int p = 0; p < 8; ++p) a += attlP[(b * 8 + p) * 64 + t];
      s_attl[t] = a;
    }
    __syncthreads();
    const int h = t & 127, kq = t >> 7;
    float a1 = 0.f, a2 = 0.f;
    const float* lp = la + ((size_t)b * Kk + kq * 16) * Mm + h;
    const float* kp = hs_key + ((size_t)b * Kk + kq * 16) * Mm + h;
    for (int j = 0; j < 16; ++j) {
      const float w = s_attl[kq * 16 + j];
      a1 += w * lp[(size_t)j * Mm];
      a2 += w * kp[(size_t)j * Mm];
    }
    float* r1 = sm;
    float* r2 = sm + 512;
    r1[kq * 128 + h] = a1; r2[kq * 128 + h] = a2;
    __syncthreads();
    if (t < 128) {
      v1[b * 128 + t] = r1[t] + r1[128 + t] + r1[256 + t] + r1[384 + t];
      v2[b * 128 + t] = r2[t] + r2[128 + t] + r2[256 + t] + r2[384 + t];
    }
    if (t == 0) {
      float s = 0.f;
      for (int j = 0; j < 64; ++j) s += s_attl[j];
      sAv[b] = s;
    }
  }
}

// ===========================================================================
// KE: finale per b (1024 threads): 5 matvecs + pair -> mapL -> fin
// ===========================================================================
__global__ __launch_bounds__(1024) void kE(
    const float* __restrict__ uP, const float* __restrict__ w1P, const float* __restrict__ w2P,
    const float* __restrict__ w0P, const float* __restrict__ v1, const float* __restrict__ v2,
    const float* __restrict__ sAv, const float* __restrict__ wT,
    const float* __restrict__ wra_b, const float* __restrict__ wrh_b,
    const float* __restrict__ wla_b, const float* __restrict__ wlh_b,
    const float* __restrict__ kR_b, const float* __restrict__ lig_rep,
    const float* __restrict__ mapL_w, const float* __restrict__ mapL_b,
    const float* __restrict__ fin_w, const float* __restrict__ fin_b,
    float* __restrict__ out)
{
  __shared__ float sV1[128], sV2[128], sU[128], sW1[128], sW2[128];
  __shared__ float sPair[264];
  __shared__ float sRed[2][8][128];
  __shared__ float s5[8];
  __shared__ float sSc[2];
  const int b = blockIdx.x, t = threadIdx.x;
  const int m = t & 127, hf = t >> 7;   // hf 0..7

  if (t < 128) {
    float u = 0.f, w1 = 0.f, w2 = 0.f;
    for (int c = 0; c < 8; ++c) {
      u  += uP[((size_t)b * 8 + c) * 128 + t];
      w1 += w1P[((size_t)b * 8 + c) * 128 + t];
      w2 += w2P[((size_t)b * 8 + c) * 128 + t];
    }
    sU[t] = u; sW1[t] = w1; sW2[t] = w2;
    sV1[t] = v1[b * 128 + t]; sV2[t] = v2[b * 128 + t];
  }
  if (t == 0) {
    float s = 0.f;
    for (int c = 0; c < 8; ++c) s += w0P[b * 8 + c];
    sSc[0] = s;           // sR = sum att_r
    sSc[1] = sAv[b];      // sA = sum att_l
  }
  __syncthreads();

  const float* wraT = wT;
  const float* wrhT = wT + 1 * 16384;
  const float* wlaT = wT + 2 * 16384;
  const float* wlhT = wT + 3 * 16384;
  const float* kRT  = wT + 6 * 16384;
  float key = 0.f, grd = 0.f;
  for (int h = hf * 16; h < hf * 16 + 16; ++h) {
    key += sV1[h] * wlaT[h * Mm + m] + sV2[h] * wlhT[h * Mm + m] + sU[h] * kRT[h * Mm + m];
    grd += sW1[h] * wraT[h * Mm + m] + sW2[h] * wrhT[h * Mm + m];
  }
  sRed[0][hf][m] = key; sRed[1][hf][m] = grd;
  __syncthreads();
  if (t < 128) {
    const float sR = sSc[0], sA = sSc[1];
    float kk = 0.f, gg = 0.f;
#pragma unroll
    for (int q = 0; q < 8; ++q) { kk += sRed[0][q][t]; gg += sRed[1][q][t]; }
    sPair[t] = kk + sA * (wla_b[t] + wlh_b[t] + kR_b[t]);
    sPair[132 + t] = gg + sR * (wra_b[t] + wrh_b[t]);
  }
  if (t < 4) sPair[128 + t] = lig_rep[b * 4 + t];
  __syncthreads();

  const int wq = t >> 6, lane = t & 63;
  if (wq < 5) {
    float acc = 0.f;
    for (int c = lane; c < 260; c += 64) acc += sPair[c] * mapL_w[wq * 260 + c];
    for (int off = 32; off; off >>= 1) acc += __shfl_xor(acc, off);
    if (lane == 0) s5[wq] = acc + mapL_b[wq];
  }
  __syncthreads();
  if (t == 0) {
    float o = fin_b[0];
    for (int l = 0; l < 5; ++l) o += s5[l] * fin_w[l];
    out[b] = o;
  }
}

// ---------------------------------------------------------------------------
extern "C" void kernel_launch(void* const* d_in, const int* in_sizes, int n_in,
                              void* d_out, int out_size, void* d_ws, size_t ws_size,
                              hipStream_t stream) {
  const float* z       = (const float*)d_in[0];
  const float* hs_grid = (const float*)d_in[1];
  const float* hs_key  = (const float*)d_in[2];
  const float* lig_rep = (const float*)d_in[3];
  const float* hs_rec  = (const float*)d_in[4];
  const float* w_Rl    = (const float*)d_in[5];
  const int*   w_mask  = (const int*)d_in[6];
  const float* wra_w = (const float*)d_in[7];  const float* wra_b = (const float*)d_in[8];
  const float* wrh_w = (const float*)d_in[9];  const float* wrh_b = (const float*)d_in[10];
  const float* wla_w = (const float*)d_in[11]; const float* wla_b = (const float*)d_in[12];
  const float* wlh_w = (const float*)d_in[13]; const float* wlh_b = (const float*)d_in[14];
  const float* z1_w  = (const float*)d_in[15];
  const float* wcR_w = (const float*)d_in[17]; const float* wcR_b = (const float*)d_in[18];
  const float* wcl_w = (const float*)d_in[19]; const float* wcl_b = (const float*)d_in[20];
  const float* kR_w  = (const float*)d_in[21]; const float* kR_b  = (const float*)d_in[22];
  const float* mapL_w = (const float*)d_in[23]; const float* mapL_b = (const float*)d_in[24];
  const float* fin_w  = (const float*)d_in[25]; const float* fin_b  = (const float*)d_in[26];
  float* out = (float*)d_out;

  float* w = (float*)d_ws;
  float* wT    = w;                           // 7*16384
  float* ra    = wT + 7 * 16384;              // B*G*M = 524288
  float* att   = ra + Bb * Gg * Mm;           // B*G*K = 262144
  float* laNum = att + Bb * Gg * Kk;          // B*NCH*K*M = 2097152 (dead after kB)
  float* laDen = laNum + Bb * NCH * Kk * Mm;  // 2097152 (dead after kB)
  float* la    = laDen + Bb * NCH * Kk * Mm;  // 65536
  float* attlP = la + Bb * Kk * Mm;           // 4096
  float* attrPM = attlP + Bb * 8 * 64;        // 4096
  float* attrPS = attrPM + Bb * 8 * 64;       // 4096
  float* att_r = attrPS + Bb * 8 * 64;        // 4096
  float* Lk    = att_r + Bb * Gg;             // B*K*M = 65536
  float* scores = Lk + Bb * Kk * Mm;          // B*N*K = 524288

  // aliases into laNum (dead after kB)
  float* pmT  = laNum;                        // 32768
  float* psT  = laNum + 32768;                // 32768
  float* uP   = laNum + 65536;                // B*8*128 = 8192
  float* w1P  = laNum + 73728;                // 8192
  float* w2P  = laNum + 81920;                // 8192
  float* w0P  = laNum + 90112;                // 64
  float* v1   = laNum + 90176;                // 1024
  float* v2   = laNum + 91200;                // 1024
  float* sAv  = laNum + 92224;                // 8

  P7 ptrs;
  ptrs.p[0] = wra_w; ptrs.p[1] = wrh_w; ptrs.p[2] = wla_w; ptrs.p[3] = wlh_w;
  ptrs.p[4] = wcR_w; ptrs.p[5] = wcl_w; ptrs.p[6] = kR_w;

  kA<<<Bb * NCH + 112, 1024, 0, stream>>>(z, hs_grid, hs_key, z1_w, ptrs, wT,
                                          ra, att, laNum, laDen);
  kB<<<448, 256, 0, stream>>>(laNum, laDen, la, att, attlP, attrPM, attrPS,
                              hs_key, wT, wcR_w, wcl_b, Lk);
  kC<<<576, 256, 0, stream>>>(att, attrPM, attrPS, att_r, hs_rec, Lk,
                              w_mask, w_Rl, scores, pmT, psT);
  kD<<<136, 512, 0, stream>>>(scores, hs_rec, pmT, psT, attlP, att_r,
                              ra, hs_grid, la, hs_key,
                              uP, w1P, w2P, w0P, v1, v2, sAv);
  kE<<<Bb, 1024, 0, stream>>>(uP, w1P, w2P, w0P, v1, v2, sAv, wT,
                              wra_b, wrh_b, wla_b, wlh_b, kR_b, lig_rep,
                              mapL_w, mapL_b, fin_w, fin_b, out);
}